// Round 5
// baseline (92.539 us; speedup 1.0000x reference)
//
#include <hip/hip_runtime.h>
#include <math.h>

// EEGSDE: OU Euler-Maruyama step with antithetic variates + ERP jump injection.
// paths[n,b,c,t] = x[b,c,t]*(1 - theta*dt) + s*sqrt(dt)*sigma*eps[n%32,b,c,t]
//                  + mask[n,b,c]*0.2*mag[n,b,c]*exp(-0.5*((t - jt[n,b,c])/10)^2)
//
// R5: COPY-SHAPED decomposition. Antithetic halves split across paired blocks
// (blockIdx.x = half, fastest-varying -> pair dispatched back-to-back, second
// eps read L3-hits). Each thread: 1 eps load -> 1 out store per iteration,
// single linear write stream per block. x hoisted to registers (R1 pattern).

#define DT_F 0.01f
#define THETA0 2.0f
#define SIGMA0 0.5f
#define JUMP_RATE 0.1f
#define JUMP_SCALE 0.2f
#define ERP_INV_W 0.1f   // 1/10

constexpr int B_ = 16;
constexpr int C_ = 64;
constexpr int T_ = 1000;
constexpr int NH_ = 32;          // N_paths / 2
constexpr int BC_ = B_ * C_;     // 1024
constexpr int CHUNKS_ = T_ / 4;  // 250 float4 chunks per row
constexpr int NH_PER_BLK = 8;    // gridDim.z = NH_/NH_PER_BLK = 4

typedef float f32x4 __attribute__((ext_vector_type(4)));

__global__ __launch_bounds__(256) void eegsde_paths_split(
    const float* __restrict__ x,            // [B,C,T]
    const float* __restrict__ theta_scale,  // [1]
    const float* __restrict__ sigma_scale,  // [1]
    const float* __restrict__ eps,          // [NH,B,C,T]
    const float* __restrict__ jump_rand,    // [N,B,C]
    const float* __restrict__ jump_mag,     // [N,B,C]
    const int*   __restrict__ jump_times,   // [N,B,C]
    float* __restrict__ out)                // [N,B,C,T]
{
    const int half = blockIdx.x;     // 0: +eps (paths 0..31), 1: -eps (32..63)
    const int bc   = blockIdx.y;     // 0..1023
    const int tc   = threadIdx.x;    // 0..255
    if (tc >= CHUNKS_) return;
    const int t0 = tc * 4;

    const float theta = THETA0 * fabsf(theta_scale[0]);
    const float sigma = SIGMA0 * fabsf(sigma_scale[0]);
    const float a = 1.0f - theta * DT_F;
    // Fold the antithetic sign into the dW scale: o = a*x + sd*e + j
    const float sd = (half ? -1.0f : 1.0f) * sqrtf(DT_F) * sigma;

    // x row chunk: loaded once, reused across 8 nh iterations.
    const f32x4 x4 = *reinterpret_cast<const f32x4*>(&x[bc * T_ + t0]);
    const float bx0 = a * x4.x;
    const float bx1 = a * x4.y;
    const float bx2 = a * x4.z;
    const float bx3 = a * x4.w;

    const float tf0 = (float)t0;
    const float tf1 = tf0 + 1.0f;
    const float tf2 = tf0 + 2.0f;
    const float tf3 = tf0 + 3.0f;

    const int nh_begin = blockIdx.z * NH_PER_BLK;

    #pragma unroll 2
    for (int i = 0; i < NH_PER_BLK; ++i) {
        const int nh = nh_begin + i;
        const size_t erow = (size_t)nh * BC_ + bc;               // eps row
        const size_t orow = (size_t)(nh + half * NH_) * BC_ + bc; // out row

        // 1 load (half=1 blocks should L3-hit behind their half=0 twin)
        const f32x4 e4 = *reinterpret_cast<const f32x4*>(&eps[erow * T_ + t0]);

        // Per-row jump scalars — wave-uniform.
        const float jr  = jump_rand[orow];
        const float amp = (jr < JUMP_RATE) ? (JUMP_SCALE * jump_mag[orow]) : 0.0f;

        float j0 = 0.f, j1 = 0.f, j2 = 0.f, j3 = 0.f;
        if (amp != 0.0f) {              // wave-uniform branch, ~90% skip
            const float jt = (float)jump_times[orow];
            const float d0 = (tf0 - jt) * ERP_INV_W;
            const float d1 = (tf1 - jt) * ERP_INV_W;
            const float d2 = (tf2 - jt) * ERP_INV_W;
            const float d3 = (tf3 - jt) * ERP_INV_W;
            j0 = amp * __expf(-0.5f * d0 * d0);
            j1 = amp * __expf(-0.5f * d1 * d1);
            j2 = amp * __expf(-0.5f * d2 * d2);
            j3 = amp * __expf(-0.5f * d3 * d3);
        }

        f32x4 o;
        o.x = bx0 + sd * e4.x + j0;
        o.y = bx1 + sd * e4.y + j1;
        o.z = bx2 + sd * e4.z + j2;
        o.w = bx3 + sd * e4.w + j3;

        // 1 store — single linear stream per block.
        *reinterpret_cast<f32x4*>(&out[orow * T_ + t0]) = o;
    }
}

extern "C" void kernel_launch(void* const* d_in, const int* in_sizes, int n_in,
                              void* d_out, int out_size, void* d_ws, size_t ws_size,
                              hipStream_t stream) {
    const float* x           = (const float*)d_in[0];
    const float* theta_scale = (const float*)d_in[1];
    const float* sigma_scale = (const float*)d_in[2];
    const float* eps         = (const float*)d_in[3];
    const float* jump_rand   = (const float*)d_in[4];
    const float* jump_mag    = (const float*)d_in[5];
    const int*   jump_times  = (const int*)d_in[6];
    float* out = (float*)d_out;

    // half fastest-varying: antithetic twins dispatched back-to-back.
    dim3 grid(2, BC_, NH_ / NH_PER_BLK);   // (2, 1024, 4) = 8192 blocks
    dim3 block(256, 1, 1);
    eegsde_paths_split<<<grid, block, 0, stream>>>(
        x, theta_scale, sigma_scale, eps, jump_rand, jump_mag, jump_times, out);
}

// Round 6
// 69.174 us; speedup vs baseline: 1.3378x; 1.3378x over previous
//
#include <hip/hip_runtime.h>
#include <math.h>

// EEGSDE: OU Euler-Maruyama step with antithetic variates + ERP jump injection.
// paths[n,b,c,t] = x[b,c,t]*(1 - theta*dt) + s*sqrt(dt)*sigma*eps[n%32,b,c,t]
//                  + mask[n,b,c]*0.2*mag[n,b,c]*exp(-0.5*((t - jt[n,b,c])/10)^2)
//
// R6: R1 structure (best so far, 82.9us) + ISOLATED nontemporal-store A/B
// (out ~= L3 capacity; evict-first should stop the write stream thrashing
// MALL against the eps read stream). Plain cached loads. 32-bit addressing.

#define DT_F 0.01f
#define THETA0 2.0f
#define SIGMA0 0.5f
#define JUMP_RATE 0.1f
#define JUMP_SCALE 0.2f
#define ERP_INV_W 0.1f   // 1/10

constexpr int B_ = 16;
constexpr int C_ = 64;
constexpr int T_ = 1000;
constexpr int NH_ = 32;          // N_paths / 2
constexpr int BC_ = B_ * C_;     // 1024
constexpr int CHUNKS_ = T_ / 4;  // 250 float4 chunks per row
constexpr int NH_PER_BLK = 8;    // gridDim.y = NH_/NH_PER_BLK = 4
constexpr uint32_t ROW_F = (uint32_t)T_;            // floats per row
constexpr uint32_t HALF_F = (uint32_t)NH_ * BC_ * T_; // 32,768,000 floats (fits u32)

typedef float f32x4 __attribute__((ext_vector_type(4)));

__global__ __launch_bounds__(256) void eegsde_paths_kernel(
    const float* __restrict__ x,            // [B,C,T]
    const float* __restrict__ theta_scale,  // [1]
    const float* __restrict__ sigma_scale,  // [1]
    const float* __restrict__ eps,          // [NH,B,C,T]
    const float* __restrict__ jump_rand,    // [N,B,C]
    const float* __restrict__ jump_mag,     // [N,B,C]
    const int*   __restrict__ jump_times,   // [N,B,C]
    float* __restrict__ out)                // [N,B,C,T]
{
    const uint32_t bc = blockIdx.x;       // 0..1023
    const uint32_t tc = threadIdx.x;      // 0..255
    if (tc >= CHUNKS_) return;
    const uint32_t t0 = tc * 4u;

    const float theta = THETA0 * fabsf(theta_scale[0]);
    const float sigma = SIGMA0 * fabsf(sigma_scale[0]);
    const float a  = 1.0f - theta * DT_F;
    const float sd = sqrtf(DT_F) * sigma;

    // x loaded once, reused across 8 nh iterations (4 MB buffer, L2-resident).
    const f32x4 x4 = *reinterpret_cast<const f32x4*>(&x[bc * ROW_F + t0]);
    const float bx0 = a * x4.x;
    const float bx1 = a * x4.y;
    const float bx2 = a * x4.z;
    const float bx3 = a * x4.w;

    const float tf0 = (float)t0;
    const float tf1 = tf0 + 1.0f;
    const float tf2 = tf0 + 2.0f;
    const float tf3 = tf0 + 3.0f;

    const uint32_t nh_begin = blockIdx.y * NH_PER_BLK;

    #pragma unroll 2
    for (uint32_t i = 0; i < NH_PER_BLK; ++i) {
        const uint32_t nh   = nh_begin + i;
        const uint32_t row  = nh * BC_ + bc;        // param row, path nh
        const uint32_t row1 = row + NH_ * BC_;      // param row, path nh+32
        const uint32_t off  = row * ROW_F + t0;     // float offset (fits u32)

        // Plain cached load (single-use, but L3 pollution handled by nt stores).
        const f32x4 e4 = *reinterpret_cast<const f32x4*>(&eps[off]);

        // Block-uniform jump scalars -> scalarized broadcast loads.
        const float amp0 = (jump_rand[row]  < JUMP_RATE) ? (JUMP_SCALE * jump_mag[row])  : 0.0f;
        const float amp1 = (jump_rand[row1] < JUMP_RATE) ? (JUMP_SCALE * jump_mag[row1]) : 0.0f;
        const float jt0 = (float)jump_times[row];
        const float jt1 = (float)jump_times[row1];

        const float dw0 = sd * e4.x;
        const float dw1 = sd * e4.y;
        const float dw2 = sd * e4.z;
        const float dw3 = sd * e4.w;

        const float d00 = (tf0 - jt0) * ERP_INV_W;
        const float d01 = (tf1 - jt0) * ERP_INV_W;
        const float d02 = (tf2 - jt0) * ERP_INV_W;
        const float d03 = (tf3 - jt0) * ERP_INV_W;
        const float d10 = (tf0 - jt1) * ERP_INV_W;
        const float d11 = (tf1 - jt1) * ERP_INV_W;
        const float d12 = (tf2 - jt1) * ERP_INV_W;
        const float d13 = (tf3 - jt1) * ERP_INV_W;

        const float j00 = amp0 * __expf(-0.5f * d00 * d00);
        const float j01 = amp0 * __expf(-0.5f * d01 * d01);
        const float j02 = amp0 * __expf(-0.5f * d02 * d02);
        const float j03 = amp0 * __expf(-0.5f * d03 * d03);
        const float j10 = amp1 * __expf(-0.5f * d10 * d10);
        const float j11 = amp1 * __expf(-0.5f * d11 * d11);
        const float j12 = amp1 * __expf(-0.5f * d12 * d12);
        const float j13 = amp1 * __expf(-0.5f * d13 * d13);

        f32x4 o0, o1;
        o0.x = bx0 + dw0 + j00;
        o0.y = bx1 + dw1 + j01;
        o0.z = bx2 + dw2 + j02;
        o0.w = bx3 + dw3 + j03;
        o1.x = bx0 - dw0 + j10;
        o1.y = bx1 - dw1 + j11;
        o1.z = bx2 - dw2 + j12;
        o1.w = bx3 - dw3 + j13;

        // Nontemporal stores: evict-first, don't thrash the 256MB L3 with a
        // 262MB single-use write stream.
        __builtin_nontemporal_store(o0, reinterpret_cast<f32x4*>(&out[off]));
        __builtin_nontemporal_store(o1, reinterpret_cast<f32x4*>(&out[off + HALF_F]));
    }
}

extern "C" void kernel_launch(void* const* d_in, const int* in_sizes, int n_in,
                              void* d_out, int out_size, void* d_ws, size_t ws_size,
                              hipStream_t stream) {
    const float* x           = (const float*)d_in[0];
    const float* theta_scale = (const float*)d_in[1];
    const float* sigma_scale = (const float*)d_in[2];
    const float* eps         = (const float*)d_in[3];
    const float* jump_rand   = (const float*)d_in[4];
    const float* jump_mag    = (const float*)d_in[5];
    const int*   jump_times  = (const int*)d_in[6];
    float* out = (float*)d_out;

    dim3 grid(BC_, NH_ / NH_PER_BLK, 1);  // (1024, 4)
    dim3 block(256, 1, 1);
    eegsde_paths_kernel<<<grid, block, 0, stream>>>(
        x, theta_scale, sigma_scale, eps, jump_rand, jump_mag, jump_times, out);
}